// Round 2
// baseline (699.078 us; speedup 1.0000x reference)
//
#include <hip/hip_runtime.h>

#define NN 200000
#define NE 1000000
#define DD 64

typedef __bf16 bf16x8 __attribute__((ext_vector_type(8)));
typedef float  f32x4  __attribute__((ext_vector_type(4)));

// Load 8 consecutive f32 and round-to-nearest-even into a bf16x8 fragment.
static __device__ __forceinline__ bf16x8 pack8(const float* __restrict__ p) {
    float4 a = *reinterpret_cast<const float4*>(p);
    float4 b = *reinterpret_cast<const float4*>(p + 4);
    bf16x8 r;
    r[0] = (__bf16)a.x; r[1] = (__bf16)a.y; r[2] = (__bf16)a.z; r[3] = (__bf16)a.w;
    r[4] = (__bf16)b.x; r[5] = (__bf16)b.y; r[6] = (__bf16)b.z; r[7] = (__bf16)b.w;
    return r;
}

__global__ __launch_bounds__(256) void gcn_mfma_kernel(
    const int* __restrict__ src, const int* __restrict__ dst,
    const float* __restrict__ review, const float* __restrict__ ci,
    const float* __restrict__ W1, const float* __restrict__ W2,
    const float* __restrict__ f2, const float* __restrict__ f3,
    float* __restrict__ out)
{
    float* out_rst = out;                          // (feature2[src] + review@W2^T) pass
    float* out_re  = out + (size_t)NN * DD;        // review@W1^T pass
    float* out_id  = out + 2 * (size_t)NN * DD;    // feature3[src] pass

    const int lane = threadIdx.x & 63;
    const int l16  = lane & 15;
    const int lq   = lane >> 4;
    const int wid  = blockIdx.x * (blockDim.x >> 6) + (threadIdx.x >> 6);
    const int nw   = gridDim.x * (blockDim.x >> 6);

    // B fragments: D = A@B with B[k][col] = W[col][k]  (so R = X @ W^T).
    // Lane holds B[k = kk*32 + lq*8 .. +7][col = c*16 + l16]  ==
    //            W[c*16 + l16][kk*32 + lq*8 .. +7]  — contiguous 8 floats.
    bf16x8 w1f[4][2], w2f[4][2];
#pragma unroll
    for (int c = 0; c < 4; ++c) {
#pragma unroll
        for (int kk = 0; kk < 2; ++kk) {
            const int off = (c * 16 + l16) * DD + kk * 32 + lq * 8;
            w1f[c][kk] = pack8(W1 + off);
            w2f[c][kk] = pack8(W2 + off);
        }
    }

    const f32x4 zero = {0.f, 0.f, 0.f, 0.f};
    const int ntiles = NE / 16;

    for (int t = wid; t < ntiles; t += nw) {
        const int e0 = t * 16;

        // A fragments: lane holds X[e0 + l16][kk*32 + lq*8 .. +7].
        const float* xr = review + (size_t)(e0 + l16) * DD + lq * 8;
        const bf16x8 a0 = pack8(xr);
        const bf16x8 a1 = pack8(xr + 32);

        f32x4 acc1[4], acc2[4];
#pragma unroll
        for (int c = 0; c < 4; ++c) { acc1[c] = zero; acc2[c] = zero; }

#pragma unroll
        for (int c = 0; c < 4; ++c) {
            acc1[c] = __builtin_amdgcn_mfma_f32_16x16x32_bf16(a0, w1f[c][0], acc1[c], 0, 0, 0);
            acc1[c] = __builtin_amdgcn_mfma_f32_16x16x32_bf16(a1, w1f[c][1], acc1[c], 0, 0, 0);
            acc2[c] = __builtin_amdgcn_mfma_f32_16x16x32_bf16(a0, w2f[c][0], acc2[c], 0, 0, 0);
            acc2[c] = __builtin_amdgcn_mfma_f32_16x16x32_bf16(a1, w2f[c][1], acc2[c], 0, 0, 0);
        }

        // Per-lane edge metadata: C/D rows covered by this lane are lq*4 + i.
        int   sA[4], dA[4];
        float cf[4];
#pragma unroll
        for (int i = 0; i < 4; ++i) {
            const int e = e0 + lq * 4 + i;
            const int s = src[e];
            const int d = dst[e];
            sA[i] = s; dA[i] = d;
            cf[i] = ci[s] * ci[d];   // fold ci_src * ci_dst into the message
        }

        // Scatter: for fixed i, lanes 0..15 of each quarter hit 64B-contiguous
        // segments of 4 distinct edge rows.
#pragma unroll
        for (int i = 0; i < 4; ++i) {
            const size_t so = (size_t)sA[i] * DD;
            const size_t dofs = (size_t)dA[i] * DD;
            const float c_ = cf[i];
#pragma unroll
            for (int c = 0; c < 4; ++c) {
                const int col = c * 16 + l16;
                atomicAdd(out_re  + dofs + col, acc1[c][i] * c_);
                atomicAdd(out_rst + dofs + col, (f2[so + col] + acc2[c][i]) * c_);
                atomicAdd(out_id  + dofs + col, f3[so + col] * c_);
            }
        }
    }
}

extern "C" void kernel_launch(void* const* d_in, const int* in_sizes, int n_in,
                              void* d_out, int out_size, void* d_ws, size_t ws_size,
                              hipStream_t stream) {
    const int*   src    = (const int*)d_in[0];
    const int*   dst    = (const int*)d_in[1];
    const float* review = (const float*)d_in[2];
    const float* ci     = (const float*)d_in[3];
    // d_in[4] = feature (unused by the reference computation)
    const float* W1     = (const float*)d_in[5];
    const float* W2     = (const float*)d_in[6];
    const float* f2     = (const float*)d_in[7];
    const float* f3     = (const float*)d_in[8];
    float* out = (float*)d_out;

    hipMemsetAsync(out, 0, (size_t)out_size * sizeof(float), stream);

    const int block = 256;   // 4 waves/block
    const int grid  = 2048;  // 8192 waves, grid-stride over 62500 16-edge tiles
    gcn_mfma_kernel<<<grid, block, 0, stream>>>(src, dst, review, ci, W1, W2, f2, f3, out);
}

// Round 3
// 475.659 us; speedup vs baseline: 1.4697x; 1.4697x over previous
//
#include <hip/hip_runtime.h>

#define NN 200000
#define NE 1000000
#define DD 64
#define NCHUNK 196   // ceil(NN / 1024)

typedef __bf16 bf16x8 __attribute__((ext_vector_type(8)));
typedef float  f32x4  __attribute__((ext_vector_type(4)));

// Load 8 consecutive f32 and convert to bf16x8 (RNE).
static __device__ __forceinline__ bf16x8 pack8(const float* __restrict__ p) {
    float4 a = *reinterpret_cast<const float4*>(p);
    float4 b = *reinterpret_cast<const float4*>(p + 4);
    bf16x8 r;
    r[0] = (__bf16)a.x; r[1] = (__bf16)a.y; r[2] = (__bf16)a.z; r[3] = (__bf16)a.w;
    r[4] = (__bf16)b.x; r[5] = (__bf16)b.y; r[6] = (__bf16)b.z; r[7] = (__bf16)b.w;
    return r;
}

// ---------- CSR construction ----------

__global__ __launch_bounds__(256) void k_hist(const int* __restrict__ dst,
                                              int* __restrict__ counts) {
    for (int e = blockIdx.x * blockDim.x + threadIdx.x; e < NE;
         e += gridDim.x * blockDim.x)
        atomicAdd(&counts[dst[e]], 1);
}

// Per-1024-element chunk sums.
__global__ __launch_bounds__(256) void k_chunk_sums(const int* __restrict__ counts,
                                                    int* __restrict__ csum) {
    const int b = blockIdx.x, tid = threadIdx.x;
    const int base = b * 1024 + tid * 4;
    int s = 0;
#pragma unroll
    for (int j = 0; j < 4; ++j) {
        const int i = base + j;
        if (i < NN) s += counts[i];
    }
#pragma unroll
    for (int d = 32; d > 0; d >>= 1) s += __shfl_down(s, d);
    __shared__ int wsum[4];
    if ((tid & 63) == 0) wsum[tid >> 6] = s;
    __syncthreads();
    if (tid == 0) csum[b] = wsum[0] + wsum[1] + wsum[2] + wsum[3];
}

// Serial exclusive scan of the 196 chunk sums (tiny).
__global__ void k_scan_chunks(const int* __restrict__ csum, int* __restrict__ cofs) {
    if (threadIdx.x == 0 && blockIdx.x == 0) {
        int acc = 0;
        for (int i = 0; i < NCHUNK; ++i) { cofs[i] = acc; acc += csum[i]; }
    }
}

// Per-chunk exclusive scan + global chunk offset -> offs[] and cursor[].
__global__ __launch_bounds__(256) void k_chunk_scan(const int* __restrict__ counts,
                                                    const int* __restrict__ cofs,
                                                    int* __restrict__ offs,
                                                    int* __restrict__ cursor) {
    const int b = blockIdx.x, tid = threadIdx.x;
    const int lane = tid & 63, wv = tid >> 6;
    const int base = b * 1024 + tid * 4;
    int c[4];
#pragma unroll
    for (int j = 0; j < 4; ++j) {
        const int i = base + j;
        c[j] = (i < NN) ? counts[i] : 0;
    }
    const int ls = c[0] + c[1] + c[2] + c[3];
    int v = ls;
#pragma unroll
    for (int d = 1; d < 64; d <<= 1) {
        const int u = __shfl_up(v, d);
        if (lane >= d) v += u;
    }
    __shared__ int wsum[4];
    if (lane == 63) wsum[wv] = v;
    __syncthreads();
    int wbase = 0;
    for (int w = 0; w < wv; ++w) wbase += wsum[w];
    int excl = cofs[b] + wbase + (v - ls);
#pragma unroll
    for (int j = 0; j < 4; ++j) {
        const int i = base + j;
        if (i < NN) { offs[i] = excl; cursor[i] = excl; }
        excl += c[j];
    }
}

__global__ __launch_bounds__(256) void k_permfill(const int* __restrict__ dst,
                                                  int* __restrict__ cursor,
                                                  int* __restrict__ perm) {
    for (int e = blockIdx.x * blockDim.x + threadIdx.x; e < NE;
         e += gridDim.x * blockDim.x) {
        const int pos = atomicAdd(&cursor[dst[e]], 1);
        perm[pos] = e;
    }
}

// ---------- Pull phase: one wave per dst node, no atomics ----------
// hx[d]      = ci_d * sum_e review[e] * ci_src
// out_rst[d] = ci_d * sum_e f2[src]   * ci_src   (partial; GEMM adds W2 @ hx)
// out_id[d]  = ci_d * sum_e f3[src]   * ci_src   (final)
__global__ __launch_bounds__(256) void k_pull(
    const int* __restrict__ src, const int* __restrict__ perm,
    const int* __restrict__ offs, const int* __restrict__ counts,
    const float* __restrict__ review, const float* __restrict__ ci,
    const float* __restrict__ f2, const float* __restrict__ f3,
    float* __restrict__ hx, float* __restrict__ out_rst, float* __restrict__ out_id)
{
    const int wid = blockIdx.x * (blockDim.x >> 6) + (threadIdx.x >> 6);
    if (wid >= NN) return;
    const int lane = threadIdx.x & 63;
    const int beg = offs[wid];
    const int cnt = counts[wid];

    float hxv = 0.f, s2 = 0.f, s3 = 0.f;
    for (int k = 0; k < cnt; ++k) {
        const int e = perm[beg + k];
        const int s = src[e];
        const float cis = ci[s];
        hxv = fmaf(review[(size_t)e * DD + lane], cis, hxv);
        s2  = fmaf(f2[(size_t)s * DD + lane], cis, s2);
        s3  = fmaf(f3[(size_t)s * DD + lane], cis, s3);
    }
    const float cid = ci[wid];
    hx[(size_t)wid * DD + lane]      = hxv * cid;
    out_rst[(size_t)wid * DD + lane] = s2 * cid;
    out_id[(size_t)wid * DD + lane]  = s3 * cid;
}

// ---------- Node GEMM: out_re = hx @ W1^T ; out_rst += hx @ W2^T ----------
__global__ __launch_bounds__(256) void k_gemm(
    const float* __restrict__ hx, const float* __restrict__ W1,
    const float* __restrict__ W2, float* __restrict__ out_re,
    float* __restrict__ out_rst)
{
    const int lane = threadIdx.x & 63;
    const int l16  = lane & 15;
    const int lq   = lane >> 4;
    const int t = blockIdx.x * (blockDim.x >> 6) + (threadIdx.x >> 6);
    if (t >= NN / 16) return;

    bf16x8 w1f[4][2], w2f[4][2];
#pragma unroll
    for (int c = 0; c < 4; ++c)
#pragma unroll
        for (int kk = 0; kk < 2; ++kk) {
            const int off = (c * 16 + l16) * DD + kk * 32 + lq * 8;
            w1f[c][kk] = pack8(W1 + off);
            w2f[c][kk] = pack8(W2 + off);
        }

    const int n0 = t * 16;
    const float* xr = hx + (size_t)(n0 + l16) * DD + lq * 8;
    const bf16x8 a0 = pack8(xr);
    const bf16x8 a1 = pack8(xr + 32);

    const f32x4 zero = {0.f, 0.f, 0.f, 0.f};
    f32x4 acc1[4], acc2[4];
#pragma unroll
    for (int c = 0; c < 4; ++c) { acc1[c] = zero; acc2[c] = zero; }
#pragma unroll
    for (int c = 0; c < 4; ++c) {
        acc1[c] = __builtin_amdgcn_mfma_f32_16x16x32_bf16(a0, w1f[c][0], acc1[c], 0, 0, 0);
        acc1[c] = __builtin_amdgcn_mfma_f32_16x16x32_bf16(a1, w1f[c][1], acc1[c], 0, 0, 0);
        acc2[c] = __builtin_amdgcn_mfma_f32_16x16x32_bf16(a0, w2f[c][0], acc2[c], 0, 0, 0);
        acc2[c] = __builtin_amdgcn_mfma_f32_16x16x32_bf16(a1, w2f[c][1], acc2[c], 0, 0, 0);
    }

#pragma unroll
    for (int i = 0; i < 4; ++i) {
        const size_t n = (size_t)(n0 + lq * 4 + i) * DD;
#pragma unroll
        for (int c = 0; c < 4; ++c) {
            const int col = c * 16 + l16;
            out_re[n + col] = acc1[c][i];
            out_rst[n + col] += acc2[c][i];
        }
    }
}

// ---------- Fallback (round-2 proven kernel) if ws too small ----------
__global__ __launch_bounds__(256) void gcn_mfma_kernel(
    const int* __restrict__ src, const int* __restrict__ dst,
    const float* __restrict__ review, const float* __restrict__ ci,
    const float* __restrict__ W1, const float* __restrict__ W2,
    const float* __restrict__ f2, const float* __restrict__ f3,
    float* __restrict__ out)
{
    float* out_rst = out;
    float* out_re  = out + (size_t)NN * DD;
    float* out_id  = out + 2 * (size_t)NN * DD;
    const int lane = threadIdx.x & 63;
    const int l16  = lane & 15;
    const int lq   = lane >> 4;
    const int wid  = blockIdx.x * (blockDim.x >> 6) + (threadIdx.x >> 6);
    const int nw   = gridDim.x * (blockDim.x >> 6);

    bf16x8 w1f[4][2], w2f[4][2];
#pragma unroll
    for (int c = 0; c < 4; ++c)
#pragma unroll
        for (int kk = 0; kk < 2; ++kk) {
            const int off = (c * 16 + l16) * DD + kk * 32 + lq * 8;
            w1f[c][kk] = pack8(W1 + off);
            w2f[c][kk] = pack8(W2 + off);
        }
    const f32x4 zero = {0.f, 0.f, 0.f, 0.f};
    for (int t = wid; t < NE / 16; t += nw) {
        const int e0 = t * 16;
        const float* xr = review + (size_t)(e0 + l16) * DD + lq * 8;
        const bf16x8 a0 = pack8(xr);
        const bf16x8 a1 = pack8(xr + 32);
        f32x4 acc1[4], acc2[4];
#pragma unroll
        for (int c = 0; c < 4; ++c) { acc1[c] = zero; acc2[c] = zero; }
#pragma unroll
        for (int c = 0; c < 4; ++c) {
            acc1[c] = __builtin_amdgcn_mfma_f32_16x16x32_bf16(a0, w1f[c][0], acc1[c], 0, 0, 0);
            acc1[c] = __builtin_amdgcn_mfma_f32_16x16x32_bf16(a1, w1f[c][1], acc1[c], 0, 0, 0);
            acc2[c] = __builtin_amdgcn_mfma_f32_16x16x32_bf16(a0, w2f[c][0], acc2[c], 0, 0, 0);
            acc2[c] = __builtin_amdgcn_mfma_f32_16x16x32_bf16(a1, w2f[c][1], acc2[c], 0, 0, 0);
        }
        int sA[4], dA[4]; float cf[4];
#pragma unroll
        for (int i = 0; i < 4; ++i) {
            const int e = e0 + lq * 4 + i;
            sA[i] = src[e]; dA[i] = dst[e];
            cf[i] = ci[sA[i]] * ci[dA[i]];
        }
#pragma unroll
        for (int i = 0; i < 4; ++i) {
            const size_t so = (size_t)sA[i] * DD;
            const size_t dofs = (size_t)dA[i] * DD;
            const float c_ = cf[i];
#pragma unroll
            for (int c = 0; c < 4; ++c) {
                const int col = c * 16 + l16;
                atomicAdd(out_re  + dofs + col, acc1[c][i] * c_);
                atomicAdd(out_rst + dofs + col, (f2[so + col] + acc2[c][i]) * c_);
                atomicAdd(out_id  + dofs + col, f3[so + col] * c_);
            }
        }
    }
}

extern "C" void kernel_launch(void* const* d_in, const int* in_sizes, int n_in,
                              void* d_out, int out_size, void* d_ws, size_t ws_size,
                              hipStream_t stream) {
    const int*   src    = (const int*)d_in[0];
    const int*   dst    = (const int*)d_in[1];
    const float* review = (const float*)d_in[2];
    const float* ci     = (const float*)d_in[3];
    // d_in[4] = feature (unused by the reference computation)
    const float* W1     = (const float*)d_in[5];
    const float* W2     = (const float*)d_in[6];
    const float* f2     = (const float*)d_in[7];
    const float* f3     = (const float*)d_in[8];
    float* out = (float*)d_out;
    float* out_rst = out;
    float* out_re  = out + (size_t)NN * DD;
    float* out_id  = out + 2 * (size_t)NN * DD;

    // Workspace carve: counts | offs | cursor | csum | cofs | perm | hx
    const size_t NEED = sizeof(int) * ((size_t)3 * NN + 512 + NE) +
                        sizeof(float) * (size_t)NN * DD;
    if (ws_size < NEED) {
        // Fallback: proven single-kernel atomic version.
        hipMemsetAsync(out, 0, (size_t)out_size * sizeof(float), stream);
        gcn_mfma_kernel<<<2048, 256, 0, stream>>>(src, dst, review, ci, W1, W2, f2, f3, out);
        return;
    }

    char* w = (char*)d_ws;
    int* counts = (int*)w;           w += (size_t)NN * 4;
    int* offs   = (int*)w;           w += (size_t)NN * 4;
    int* cursor = (int*)w;           w += (size_t)NN * 4;
    int* csum   = (int*)w;           w += 256 * 4;
    int* cofs   = (int*)w;           w += 256 * 4;
    int* perm   = (int*)w;           w += (size_t)NE * 4;
    float* hx   = (float*)w;

    hipMemsetAsync(counts, 0, (size_t)NN * 4, stream);
    k_hist      <<<1024, 256, 0, stream>>>(dst, counts);
    k_chunk_sums<<<NCHUNK, 256, 0, stream>>>(counts, csum);
    k_scan_chunks<<<1, 64, 0, stream>>>(csum, cofs);
    k_chunk_scan<<<NCHUNK, 256, 0, stream>>>(counts, cofs, offs, cursor);
    k_permfill  <<<1024, 256, 0, stream>>>(dst, cursor, perm);
    k_pull      <<<NN / 4, 256, 0, stream>>>(src, perm, offs, counts, review, ci, f2, f3,
                                             hx, out_rst, out_id);
    k_gemm      <<<(NN / 16 + 3) / 4, 256, 0, stream>>>(hx, W1, W2, out_re, out_rst);
}

// Round 4
// 354.128 us; speedup vs baseline: 1.9741x; 1.3432x over previous
//
#include <hip/hip_runtime.h>

#define NN 200000
#define NE 1000000
#define DD 64
#define NCHUNK 196   // ceil(NN / 1024)

typedef __bf16 bf16x8 __attribute__((ext_vector_type(8)));
typedef float  f32x4  __attribute__((ext_vector_type(4)));

static __device__ __forceinline__ bf16x8 pack8(const float* __restrict__ p) {
    float4 a = *reinterpret_cast<const float4*>(p);
    float4 b = *reinterpret_cast<const float4*>(p + 4);
    bf16x8 r;
    r[0] = (__bf16)a.x; r[1] = (__bf16)a.y; r[2] = (__bf16)a.z; r[3] = (__bf16)a.w;
    r[4] = (__bf16)b.x; r[5] = (__bf16)b.y; r[6] = (__bf16)b.z; r[7] = (__bf16)b.w;
    return r;
}

// ---------- CSR construction ----------

__global__ __launch_bounds__(256) void k_hist(const int* __restrict__ dst,
                                              int* __restrict__ counts) {
    for (int e = blockIdx.x * blockDim.x + threadIdx.x; e < NE;
         e += gridDim.x * blockDim.x)
        atomicAdd(&counts[dst[e]], 1);
}

__global__ __launch_bounds__(256) void k_chunk_sums(const int* __restrict__ counts,
                                                    int* __restrict__ csum) {
    const int b = blockIdx.x, tid = threadIdx.x;
    const int base = b * 1024 + tid * 4;
    int s = 0;
#pragma unroll
    for (int j = 0; j < 4; ++j) {
        const int i = base + j;
        if (i < NN) s += counts[i];
    }
#pragma unroll
    for (int d = 32; d > 0; d >>= 1) s += __shfl_down(s, d);
    __shared__ int wsum[4];
    if ((tid & 63) == 0) wsum[tid >> 6] = s;
    __syncthreads();
    if (tid == 0) csum[b] = wsum[0] + wsum[1] + wsum[2] + wsum[3];
}

__global__ void k_scan_chunks(const int* __restrict__ csum, int* __restrict__ cofs) {
    if (threadIdx.x == 0 && blockIdx.x == 0) {
        int acc = 0;
        for (int i = 0; i < NCHUNK; ++i) { cofs[i] = acc; acc += csum[i]; }
    }
}

__global__ __launch_bounds__(256) void k_chunk_scan(const int* __restrict__ counts,
                                                    const int* __restrict__ cofs,
                                                    int* __restrict__ offs,
                                                    int* __restrict__ cursor) {
    const int b = blockIdx.x, tid = threadIdx.x;
    const int lane = tid & 63, wv = tid >> 6;
    const int base = b * 1024 + tid * 4;
    int c[4];
#pragma unroll
    for (int j = 0; j < 4; ++j) {
        const int i = base + j;
        c[j] = (i < NN) ? counts[i] : 0;
    }
    const int ls = c[0] + c[1] + c[2] + c[3];
    int v = ls;
#pragma unroll
    for (int d = 1; d < 64; d <<= 1) {
        const int u = __shfl_up(v, d);
        if (lane >= d) v += u;
    }
    __shared__ int wsum[4];
    if (lane == 63) wsum[wv] = v;
    __syncthreads();
    int wbase = 0;
    for (int w = 0; w < wv; ++w) wbase += wsum[w];
    int excl = cofs[b] + wbase + (v - ls);
#pragma unroll
    for (int j = 0; j < 4; ++j) {
        const int i = base + j;
        if (i < NN) { offs[i] = excl; cursor[i] = excl; }
        excl += c[j];
    }
}

// Fill CSR slots with pre-gathered metadata: epack = {edge, src}, ecis = ci[src].
__global__ __launch_bounds__(256) void k_permfill(const int* __restrict__ dst,
                                                  const int* __restrict__ src,
                                                  const float* __restrict__ ci,
                                                  int* __restrict__ cursor,
                                                  int2* __restrict__ epack,
                                                  float* __restrict__ ecis) {
    for (int e = blockIdx.x * blockDim.x + threadIdx.x; e < NE;
         e += gridDim.x * blockDim.x) {
        const int s = src[e];
        const int pos = atomicAdd(&cursor[dst[e]], 1);
        epack[pos] = make_int2(e, s);
        ecis[pos] = ci[s];
    }
}

// ---------- Pull: one wave per dst node, quarter-wave per edge ----------
__global__ __launch_bounds__(256) void k_pull(
    const int2* __restrict__ epack, const float* __restrict__ ecis,
    const int* __restrict__ offs, const int* __restrict__ counts,
    const float* __restrict__ review, const float* __restrict__ ci,
    const float* __restrict__ f2, const float* __restrict__ f3,
    float* __restrict__ hx, float* __restrict__ out_rst, float* __restrict__ out_id)
{
    const int wid = blockIdx.x * (blockDim.x >> 6) + (threadIdx.x >> 6);
    if (wid >= NN) return;
    const int lane = threadIdx.x & 63;
    const int l16  = lane & 15;
    const int lq   = lane >> 4;
    const int beg = offs[wid];
    const int cnt = counts[wid];

    float4 ax = {0.f, 0.f, 0.f, 0.f};
    float4 a2 = {0.f, 0.f, 0.f, 0.f};
    float4 a3 = {0.f, 0.f, 0.f, 0.f};

    // Quarter q handles edges k = q, q+4, q+8, ... ; 16B per lane per row.
    for (int k = lq; k < cnt; k += 4) {
        const int pos = beg + k;
        const int2 es = epack[pos];      // {edge, src}
        const float cis = ecis[pos];
        const float4 r  = *reinterpret_cast<const float4*>(review + (size_t)es.x * DD + l16 * 4);
        const float4 p2 = *reinterpret_cast<const float4*>(f2     + (size_t)es.y * DD + l16 * 4);
        const float4 p3 = *reinterpret_cast<const float4*>(f3     + (size_t)es.y * DD + l16 * 4);
        ax.x = fmaf(r.x, cis, ax.x);  ax.y = fmaf(r.y, cis, ax.y);
        ax.z = fmaf(r.z, cis, ax.z);  ax.w = fmaf(r.w, cis, ax.w);
        a2.x = fmaf(p2.x, cis, a2.x); a2.y = fmaf(p2.y, cis, a2.y);
        a2.z = fmaf(p2.z, cis, a2.z); a2.w = fmaf(p2.w, cis, a2.w);
        a3.x = fmaf(p3.x, cis, a3.x); a3.y = fmaf(p3.y, cis, a3.y);
        a3.z = fmaf(p3.z, cis, a3.z); a3.w = fmaf(p3.w, cis, a3.w);
    }

    // Reduce the 4 quarter-partials: lanes l, l^16, l^32, l^48 hold the same
    // feature slice (l16*4 .. +3).
#pragma unroll
    for (int m = 16; m <= 32; m <<= 1) {
        ax.x += __shfl_xor(ax.x, m); ax.y += __shfl_xor(ax.y, m);
        ax.z += __shfl_xor(ax.z, m); ax.w += __shfl_xor(ax.w, m);
        a2.x += __shfl_xor(a2.x, m); a2.y += __shfl_xor(a2.y, m);
        a2.z += __shfl_xor(a2.z, m); a2.w += __shfl_xor(a2.w, m);
        a3.x += __shfl_xor(a3.x, m); a3.y += __shfl_xor(a3.y, m);
        a3.z += __shfl_xor(a3.z, m); a3.w += __shfl_xor(a3.w, m);
    }

    if (lq == 0) {
        const float cid = ci[wid];
        const size_t o = (size_t)wid * DD + l16 * 4;
        float4 hv = {ax.x * cid, ax.y * cid, ax.z * cid, ax.w * cid};
        float4 v2 = {a2.x * cid, a2.y * cid, a2.z * cid, a2.w * cid};
        float4 v3 = {a3.x * cid, a3.y * cid, a3.z * cid, a3.w * cid};
        *reinterpret_cast<float4*>(hx + o)      = hv;
        *reinterpret_cast<float4*>(out_rst + o) = v2;
        *reinterpret_cast<float4*>(out_id + o)  = v3;
    }
}

// ---------- Node GEMM: out_re = hx @ W1^T ; out_rst += hx @ W2^T ----------
__global__ __launch_bounds__(256) void k_gemm(
    const float* __restrict__ hx, const float* __restrict__ W1,
    const float* __restrict__ W2, float* __restrict__ out_re,
    float* __restrict__ out_rst)
{
    const int lane = threadIdx.x & 63;
    const int l16  = lane & 15;
    const int lq   = lane >> 4;
    const int t = blockIdx.x * (blockDim.x >> 6) + (threadIdx.x >> 6);
    if (t >= NN / 16) return;

    bf16x8 w1f[4][2], w2f[4][2];
#pragma unroll
    for (int c = 0; c < 4; ++c)
#pragma unroll
        for (int kk = 0; kk < 2; ++kk) {
            const int off = (c * 16 + l16) * DD + kk * 32 + lq * 8;
            w1f[c][kk] = pack8(W1 + off);
            w2f[c][kk] = pack8(W2 + off);
        }

    const int n0 = t * 16;
    const float* xr = hx + (size_t)(n0 + l16) * DD + lq * 8;
    const bf16x8 a0 = pack8(xr);
    const bf16x8 a1 = pack8(xr + 32);

    const f32x4 zero = {0.f, 0.f, 0.f, 0.f};
    f32x4 acc1[4], acc2[4];
#pragma unroll
    for (int c = 0; c < 4; ++c) { acc1[c] = zero; acc2[c] = zero; }
#pragma unroll
    for (int c = 0; c < 4; ++c) {
        acc1[c] = __builtin_amdgcn_mfma_f32_16x16x32_bf16(a0, w1f[c][0], acc1[c], 0, 0, 0);
        acc1[c] = __builtin_amdgcn_mfma_f32_16x16x32_bf16(a1, w1f[c][1], acc1[c], 0, 0, 0);
        acc2[c] = __builtin_amdgcn_mfma_f32_16x16x32_bf16(a0, w2f[c][0], acc2[c], 0, 0, 0);
        acc2[c] = __builtin_amdgcn_mfma_f32_16x16x32_bf16(a1, w2f[c][1], acc2[c], 0, 0, 0);
    }

#pragma unroll
    for (int i = 0; i < 4; ++i) {
        const size_t n = (size_t)(n0 + lq * 4 + i) * DD;
#pragma unroll
        for (int c = 0; c < 4; ++c) {
            const int col = c * 16 + l16;
            out_re[n + col] = acc1[c][i];
            out_rst[n + col] += acc2[c][i];
        }
    }
}

// ---------- Fallback (round-2 proven kernel) if ws too small ----------
__global__ __launch_bounds__(256) void gcn_mfma_kernel(
    const int* __restrict__ src, const int* __restrict__ dst,
    const float* __restrict__ review, const float* __restrict__ ci,
    const float* __restrict__ W1, const float* __restrict__ W2,
    const float* __restrict__ f2, const float* __restrict__ f3,
    float* __restrict__ out)
{
    float* out_rst = out;
    float* out_re  = out + (size_t)NN * DD;
    float* out_id  = out + 2 * (size_t)NN * DD;
    const int lane = threadIdx.x & 63;
    const int l16  = lane & 15;
    const int lq   = lane >> 4;
    const int wid  = blockIdx.x * (blockDim.x >> 6) + (threadIdx.x >> 6);
    const int nw   = gridDim.x * (blockDim.x >> 6);

    bf16x8 w1f[4][2], w2f[4][2];
#pragma unroll
    for (int c = 0; c < 4; ++c)
#pragma unroll
        for (int kk = 0; kk < 2; ++kk) {
            const int off = (c * 16 + l16) * DD + kk * 32 + lq * 8;
            w1f[c][kk] = pack8(W1 + off);
            w2f[c][kk] = pack8(W2 + off);
        }
    const f32x4 zero = {0.f, 0.f, 0.f, 0.f};
    for (int t = wid; t < NE / 16; t += nw) {
        const int e0 = t * 16;
        const float* xr = review + (size_t)(e0 + l16) * DD + lq * 8;
        const bf16x8 a0 = pack8(xr);
        const bf16x8 a1 = pack8(xr + 32);
        f32x4 acc1[4], acc2[4];
#pragma unroll
        for (int c = 0; c < 4; ++c) { acc1[c] = zero; acc2[c] = zero; }
#pragma unroll
        for (int c = 0; c < 4; ++c) {
            acc1[c] = __builtin_amdgcn_mfma_f32_16x16x32_bf16(a0, w1f[c][0], acc1[c], 0, 0, 0);
            acc1[c] = __builtin_amdgcn_mfma_f32_16x16x32_bf16(a1, w1f[c][1], acc1[c], 0, 0, 0);
            acc2[c] = __builtin_amdgcn_mfma_f32_16x16x32_bf16(a0, w2f[c][0], acc2[c], 0, 0, 0);
            acc2[c] = __builtin_amdgcn_mfma_f32_16x16x32_bf16(a1, w2f[c][1], acc2[c], 0, 0, 0);
        }
        int sA[4], dA[4]; float cf[4];
#pragma unroll
        for (int i = 0; i < 4; ++i) {
            const int e = e0 + lq * 4 + i;
            sA[i] = src[e]; dA[i] = dst[e];
            cf[i] = ci[sA[i]] * ci[dA[i]];
        }
#pragma unroll
        for (int i = 0; i < 4; ++i) {
            const size_t so = (size_t)sA[i] * DD;
            const size_t dofs = (size_t)dA[i] * DD;
            const float c_ = cf[i];
#pragma unroll
            for (int c = 0; c < 4; ++c) {
                const int col = c * 16 + l16;
                atomicAdd(out_re  + dofs + col, acc1[c][i] * c_);
                atomicAdd(out_rst + dofs + col, (f2[so + col] + acc2[c][i]) * c_);
                atomicAdd(out_id  + dofs + col, f3[so + col] * c_);
            }
        }
    }
}

extern "C" void kernel_launch(void* const* d_in, const int* in_sizes, int n_in,
                              void* d_out, int out_size, void* d_ws, size_t ws_size,
                              hipStream_t stream) {
    const int*   src    = (const int*)d_in[0];
    const int*   dst    = (const int*)d_in[1];
    const float* review = (const float*)d_in[2];
    const float* ci     = (const float*)d_in[3];
    // d_in[4] = feature (unused by the reference computation)
    const float* W1     = (const float*)d_in[5];
    const float* W2     = (const float*)d_in[6];
    const float* f2     = (const float*)d_in[7];
    const float* f3     = (const float*)d_in[8];
    float* out = (float*)d_out;
    float* out_rst = out;
    float* out_re  = out + (size_t)NN * DD;
    float* out_id  = out + 2 * (size_t)NN * DD;

    // Workspace carve: counts | offs | cursor | csum | cofs | epack | ecis | hx
    const size_t NEED = sizeof(int) * ((size_t)3 * NN + 512) +
                        sizeof(int2) * (size_t)NE + sizeof(float) * (size_t)NE +
                        sizeof(float) * (size_t)NN * DD;
    if (ws_size < NEED) {
        hipMemsetAsync(out, 0, (size_t)out_size * sizeof(float), stream);
        gcn_mfma_kernel<<<2048, 256, 0, stream>>>(src, dst, review, ci, W1, W2, f2, f3, out);
        return;
    }

    char* w = (char*)d_ws;
    int* counts  = (int*)w;   w += (size_t)NN * 4;
    int* offs    = (int*)w;   w += (size_t)NN * 4;
    int* cursor  = (int*)w;   w += (size_t)NN * 4;
    int* csum    = (int*)w;   w += 256 * 4;
    int* cofs    = (int*)w;   w += 256 * 4;
    int2* epack  = (int2*)w;  w += (size_t)NE * 8;
    float* ecis  = (float*)w; w += (size_t)NE * 4;
    float* hx    = (float*)w;

    hipMemsetAsync(counts, 0, (size_t)NN * 4, stream);
    k_hist      <<<1024, 256, 0, stream>>>(dst, counts);
    k_chunk_sums<<<NCHUNK, 256, 0, stream>>>(counts, csum);
    k_scan_chunks<<<1, 64, 0, stream>>>(csum, cofs);
    k_chunk_scan<<<NCHUNK, 256, 0, stream>>>(counts, cofs, offs, cursor);
    k_permfill  <<<1024, 256, 0, stream>>>(dst, src, ci, cursor, epack, ecis);
    k_pull      <<<NN / 4, 256, 0, stream>>>(epack, ecis, offs, counts, review, ci, f2, f3,
                                             hx, out_rst, out_id);
    k_gemm      <<<(NN / 16 + 3) / 4, 256, 0, stream>>>(hx, W1, W2, out_re, out_rst);
}